// Round 9
// baseline (72.784 us; speedup 1.0000x reference)
//
#include <hip/hip_runtime.h>

typedef __attribute__((ext_vector_type(8))) short short8;
typedef __attribute__((ext_vector_type(4))) float f32x4;

// Native __bf16 cast -> hardware cvt (RNE).
__device__ __forceinline__ short f2bf(float f) {
    __bf16 h = (__bf16)f;
    return (short)__builtin_bit_cast(unsigned short, h);
}

__device__ __forceinline__ float fast_tanh(float x) {
    float e2 = __expf(2.f * x);
    return 1.f - 2.f * __builtin_amdgcn_rcpf(e2 + 1.f);
}

__device__ __forceinline__ float fast_sigmoid(float x) {
    return __builtin_amdgcn_rcpf(1.f + __expf(-x));
}

// Kernel 0: precompute spre[btile][t][lane] = b_attn + s@W1 fragment seeds.
// Removes the serial (load s -> cvt -> MFMA) chain from every attn wave's
// prologue so NS=32 (4 waves/SIMD) is a CLEAN device-TLP test (R3 was
// confounded by this chain).
__global__ __launch_bounds__(256) void spre_kernel(
        const float* __restrict__ s_in, const float* __restrict__ W_attn,
        const float* __restrict__ b_attn, float4* __restrict__ spre_all) {
    const int tid = threadIdx.x;
    const int lane = tid & 63;
    const int wv = tid >> 6;
    const int btile = blockIdx.x * 4 + wv;   // 32 blocks -> 128 btiles
    const int b0 = btile * 16;
    const int lo = lane & 15;
    const int g  = lane >> 4;

    const float* sp = s_in + (size_t)(b0 + lo) * 32 + 8 * g;
    float4 sa = *(const float4*)sp;
    float4 sb = *(const float4*)(sp + 4);
    short8 aS;
    aS[0]=f2bf(sa.x); aS[1]=f2bf(sa.y); aS[2]=f2bf(sa.z); aS[3]=f2bf(sa.w);
    aS[4]=f2bf(sb.x); aS[5]=f2bf(sb.y); aS[6]=f2bf(sb.z); aS[7]=f2bf(sb.w);
#pragma unroll
    for (int t = 0; t < 2; ++t) {
        const float* wp = W_attn + (size_t)(16*t + lo) * 96 + 8 * g;
        float4 wa = *(const float4*)wp;
        float4 wb = *(const float4*)(wp + 4);
        short8 bW1;
        bW1[0]=f2bf(wa.x); bW1[1]=f2bf(wa.y); bW1[2]=f2bf(wa.z); bW1[3]=f2bf(wa.w);
        bW1[4]=f2bf(wb.x); bW1[5]=f2bf(wb.y); bW1[6]=f2bf(wb.z); bW1[7]=f2bf(wb.w);
        f32x4 ci;
#pragma unroll
        for (int j = 0; j < 4; ++j) ci[j] = b_attn[16*t + 4*g + j];
        f32x4 r = __builtin_amdgcn_mfma_f32_16x16x32_bf16(bW1, aS, ci, 0, 0, 0);
        float4 o; o.x = r[0]; o.y = r[1]; o.z = r[2]; o.w = r[3];
        spre_all[(btile * 2 + t) * 64 + lane] = o;
    }
}

// Kernel 1 (R9): swapped-MFMA + precomputed spre + NS=32 -> 1024 blocks,
// 4 waves/SIMD. Prologue is now ~12 independent loads (W2 frags from 12KB
// L2-hot table + spre + v). Depth-2 pipeline (R4: depth doesn't matter)
// keeps VGPR ~90 so occupancy follows the grid.
__global__ __launch_bounds__(256, 2) void attn_kernel(
        const float* __restrict__ enc, const float* __restrict__ W_attn,
        const float* __restrict__ v_attn, const float4* __restrict__ spre_all,
        float* __restrict__ ctx_part, float* __restrict__ l_part,
        int NS, int chunk) {
    const int tid  = threadIdx.x;
    const int lane = tid & 63;
    const int wv   = tid >> 6;
    const int cid  = blockIdx.x % NS;
    const int btile = (blockIdx.x / NS) * 4 + wv;
    const int b0 = btile * 16;
    const int lo = lane & 15;   // batch (B-frag col / D col)
    const int g  = lane >> 4;   // k-group; D rows d = 4g+j (+16t)

    short8 bW2[2][2];           // A-frag: W_attn[16t+lo][32+32cc+8g+e]
#pragma unroll
    for (int t = 0; t < 2; ++t)
#pragma unroll
        for (int cc = 0; cc < 2; ++cc) {
            const float* qp = W_attn + (size_t)(16*t + lo) * 96 + 32 + 32*cc + 8*g;
            float4 qa = *(const float4*)qp;
            float4 qb = *(const float4*)(qp + 4);
            short8 bb;
            bb[0]=f2bf(qa.x); bb[1]=f2bf(qa.y); bb[2]=f2bf(qa.z); bb[3]=f2bf(qa.w);
            bb[4]=f2bf(qb.x); bb[5]=f2bf(qb.y); bb[6]=f2bf(qb.z); bb[7]=f2bf(qb.w);
            bW2[t][cc] = bb;
        }
    f32x4 spre[2];
#pragma unroll
    for (int t = 0; t < 2; ++t) {
        float4 o = spre_all[(btile * 2 + t) * 64 + lane];
        spre[t][0] = o.x; spre[t][1] = o.y; spre[t][2] = o.z; spre[t][3] = o.w;
    }
    float v0[4], v1[4];
#pragma unroll
    for (int j = 0; j < 4; ++j) { v0[j] = v_attn[4*g + j]; v1[j] = v_attn[16 + 4*g + j]; }

    float ctx[16];
#pragma unroll
    for (int i = 0; i < 16; ++i) ctx[i] = 0.f;
    float l_acc = 0.f;

    const size_t rowstride = (size_t)2048 * 64;
    const float* pc = enc + (size_t)(cid * chunk) * rowstride + (size_t)(b0 + lo) * 64 + 8 * g;

    float4 c0a,c0b,c1a,c1b, n0a,n0b,n1a,n1b;
#define LOAD_ENC(P, A,Bq,C,D) { const float4* q = (const float4*)(P); A = q[0]; Bq = q[1]; C = q[8]; D = q[9]; }

#define BODY(A,Bq,C,D) { \
    short8 a0, a1; \
    a0[0]=f2bf(A.x); a0[1]=f2bf(A.y); a0[2]=f2bf(A.z); a0[3]=f2bf(A.w); \
    a0[4]=f2bf(Bq.x); a0[5]=f2bf(Bq.y); a0[6]=f2bf(Bq.z); a0[7]=f2bf(Bq.w); \
    a1[0]=f2bf(C.x); a1[1]=f2bf(C.y); a1[2]=f2bf(C.z); a1[3]=f2bf(C.w); \
    a1[4]=f2bf(D.x); a1[5]=f2bf(D.y); a1[6]=f2bf(D.z); a1[7]=f2bf(D.w); \
    f32x4 acc0 = __builtin_amdgcn_mfma_f32_16x16x32_bf16(bW2[0][0], a0, spre[0], 0,0,0); \
    acc0 = __builtin_amdgcn_mfma_f32_16x16x32_bf16(bW2[0][1], a1, acc0, 0,0,0); \
    f32x4 acc1 = __builtin_amdgcn_mfma_f32_16x16x32_bf16(bW2[1][0], a0, spre[1], 0,0,0); \
    acc1 = __builtin_amdgcn_mfma_f32_16x16x32_bf16(bW2[1][1], a1, acc1, 0,0,0); \
    float part = fast_tanh(acc0[0])*v0[0] + fast_tanh(acc0[1])*v0[1] \
               + fast_tanh(acc0[2])*v0[2] + fast_tanh(acc0[3])*v0[3] \
               + fast_tanh(acc1[0])*v1[0] + fast_tanh(acc1[1])*v1[1] \
               + fast_tanh(acc1[2])*v1[2] + fast_tanh(acc1[3])*v1[3]; \
    part += __shfl_xor(part, 16); \
    part += __shfl_xor(part, 32); \
    float w_ = __expf(part); \
    l_acc += w_; \
    ctx[0] += w_*A.x;  ctx[1] += w_*A.y;  ctx[2] += w_*A.z;  ctx[3] += w_*A.w; \
    ctx[4] += w_*Bq.x; ctx[5] += w_*Bq.y; ctx[6] += w_*Bq.z; ctx[7] += w_*Bq.w; \
    ctx[8] += w_*C.x;  ctx[9] += w_*C.y;  ctx[10] += w_*C.z; ctx[11] += w_*C.w; \
    ctx[12] += w_*D.x; ctx[13] += w_*D.y; ctx[14] += w_*D.z; ctx[15] += w_*D.w; \
}

    LOAD_ENC(pc, c0a, c0b, c1a, c1b);
    for (int i = 0; i < chunk; i += 2) {
        LOAD_ENC(pc + rowstride, n0a, n0b, n1a, n1b);
        BODY(c0a, c0b, c1a, c1b);
        if (i + 2 < chunk) { LOAD_ENC(pc + 2*rowstride, c0a, c0b, c1a, c1b); }
        BODY(n0a, n0b, n1a, n1b);
        pc += 2 * rowstride;
    }
#undef BODY
#undef LOAD_ENC

    float* cp = ctx_part + (size_t)(cid * 2048 + b0 + lo) * 64 + 8 * g;
    *(float4*)(cp)      = make_float4(ctx[0],  ctx[1],  ctx[2],  ctx[3]);
    *(float4*)(cp + 4)  = make_float4(ctx[4],  ctx[5],  ctx[6],  ctx[7]);
    *(float4*)(cp + 32) = make_float4(ctx[8],  ctx[9],  ctx[10], ctx[11]);
    *(float4*)(cp + 36) = make_float4(ctx[12], ctx[13], ctx[14], ctx[15]);
    if (lane < 16) l_part[cid * 2048 + b0 + lane] = l_acc;
}

// Kernel 2: reduce partials -> ctx, then emb + GRU + fc. 8 batches/block,
// thread = (batch_local, h<32).
__global__ __launch_bounds__(256) void finish_kernel(
        const float* __restrict__ dec_in, const float* __restrict__ s_in,
        const float* __restrict__ W_emb, const float* __restrict__ b_emb,
        const float* __restrict__ W_ih, const float* __restrict__ W_hh,
        const float* __restrict__ b_ih, const float* __restrict__ b_hh,
        const float* __restrict__ W_fc, const float* __restrict__ b_fc,
        const float* __restrict__ ctx_part, const float* __restrict__ l_part,
        float* __restrict__ out, int NS) {
    __shared__ __align__(16) float x_lds[8][80];   // [emb(16); ctx(64)]
    __shared__ __align__(16) float s_lds[8][32];
    const int tid = threadIdx.x;
    const int bl = tid >> 5;
    const int h  = tid & 31;
    const int b  = blockIdx.x * 8 + bl;

    float c0 = 0.f, c1 = 0.f, ls = 0.f;
    for (int c = 0; c < NS; ++c) {
        const float* cp = ctx_part + (size_t)(c * 2048 + b) * 64;
        c0 += cp[h];
        c1 += cp[h + 32];
        ls += l_part[c * 2048 + b];
    }
    float inv = 1.f / ls;
    x_lds[bl][16 + h] = c0 * inv;
    x_lds[bl][48 + h] = c1 * inv;
    if (h < 16) x_lds[bl][h] = fmaxf(0.f, dec_in[b] * W_emb[h] + b_emb[h]);
    s_lds[bl][h] = s_in[b * 32 + h];
    __syncthreads();

    float a_r  = b_ih[h]      + b_hh[h];
    float a_z  = b_ih[32 + h] + b_hh[32 + h];
    float gi_n = b_ih[64 + h];
    float gh_n = b_hh[64 + h];
    const float4* xv4 = (const float4*)&x_lds[bl][0];
    const float4* wr4 = (const float4*)(W_ih + 80 * h);
    const float4* wz4 = (const float4*)(W_ih + 80 * (32 + h));
    const float4* wn4 = (const float4*)(W_ih + 80 * (64 + h));
#pragma unroll
    for (int j = 0; j < 20; ++j) {
        float4 x = xv4[j], wr = wr4[j], wz = wz4[j], wn = wn4[j];
        a_r  += x.x*wr.x + x.y*wr.y + x.z*wr.z + x.w*wr.w;
        a_z  += x.x*wz.x + x.y*wz.y + x.z*wz.z + x.w*wz.w;
        gi_n += x.x*wn.x + x.y*wn.y + x.z*wn.z + x.w*wn.w;
    }
    const float4* sv4 = (const float4*)&s_lds[bl][0];
    const float4* hr4 = (const float4*)(W_hh + 32 * h);
    const float4* hz4 = (const float4*)(W_hh + 32 * (32 + h));
    const float4* hn4 = (const float4*)(W_hh + 32 * (64 + h));
#pragma unroll
    for (int j = 0; j < 8; ++j) {
        float4 x = sv4[j], wr = hr4[j], wz = hz4[j], wn = hn4[j];
        a_r  += x.x*wr.x + x.y*wr.y + x.z*wr.z + x.w*wr.w;
        a_z  += x.x*wz.x + x.y*wz.y + x.z*wz.z + x.w*wz.w;
        gh_n += x.x*wn.x + x.y*wn.y + x.z*wn.z + x.w*wn.w;
    }
    float r = fast_sigmoid(a_r);
    float z = fast_sigmoid(a_z);
    float n = fast_tanh(gi_n + r * gh_n);
    float sv = s_lds[bl][h];
    float hn = (1.f - z) * n + z * sv;
    out[2048 + b * 32 + h] = hn;

    float p = hn * W_fc[h] + x_lds[bl][16 + h] * W_fc[32 + h] + x_lds[bl][48 + h] * W_fc[64 + h];
    if (h < 16) p += x_lds[bl][h] * W_fc[96 + h];
    p += __shfl_xor(p, 1); p += __shfl_xor(p, 2); p += __shfl_xor(p, 4);
    p += __shfl_xor(p, 8); p += __shfl_xor(p, 16);
    if (h == 0) out[b] = p + b_fc[0];
}

extern "C" void kernel_launch(void* const* d_in, const int* in_sizes, int n_in,
                              void* d_out, int out_size, void* d_ws, size_t ws_size,
                              hipStream_t stream) {
    const float* dec_in = (const float*)d_in[0];
    const float* s_in   = (const float*)d_in[1];
    const float* enc    = (const float*)d_in[2];
    const float* W_attn = (const float*)d_in[3];
    const float* b_attn = (const float*)d_in[4];
    const float* v_attn = (const float*)d_in[5];
    const float* W_emb  = (const float*)d_in[6];
    const float* b_emb  = (const float*)d_in[7];
    const float* W_ih   = (const float*)d_in[8];
    const float* W_hh   = (const float*)d_in[9];
    const float* b_ih   = (const float*)d_in[10];
    const float* b_hh   = (const float*)d_in[11];
    const float* W_fc   = (const float*)d_in[12];
    const float* b_fc   = (const float*)d_in[13];
    float* out = (float*)d_out;

    int NS = 32;  // clean TLP test: 1024 blocks, 4 waves/SIMD, cheap prologue
    while (NS > 1 && ((size_t)NS * (2048u * 64u + 2048u) + 128u * 2u * 64u * 4u) * sizeof(float) > ws_size) NS >>= 1;
    int chunk = 512 / NS;
    float* ctx_part = (float*)d_ws;                       // [NS][2048][64]
    float* l_part   = ctx_part + (size_t)NS * 2048 * 64;  // [NS][2048]
    float4* spre_all = (float4*)(l_part + (size_t)NS * 2048);  // [128][2][64] float4

    spre_kernel<<<dim3(32), dim3(256), 0, stream>>>(s_in, W_attn, b_attn, spre_all);
    attn_kernel<<<dim3(32 * NS), dim3(256), 0, stream>>>(
        enc, W_attn, v_attn, spre_all, ctx_part, l_part, NS, chunk);
    finish_kernel<<<dim3(256), dim3(256), 0, stream>>>(
        dec_in, s_in, W_emb, b_emb, W_ih, W_hh, b_ih, b_hh, W_fc, b_fc,
        ctx_part, l_part, out, NS);
}

// Round 10
// 58.487 us; speedup vs baseline: 1.2444x; 1.2444x over previous
//
#include <hip/hip_runtime.h>

typedef __attribute__((ext_vector_type(8))) short short8;
typedef __attribute__((ext_vector_type(4))) float f32x4;

// Native __bf16 cast -> hardware cvt (RNE).
__device__ __forceinline__ short f2bf(float f) {
    __bf16 h = (__bf16)f;
    return (short)__builtin_bit_cast(unsigned short, h);
}

__device__ __forceinline__ float fast_tanh(float x) {
    float e2 = __expf(2.f * x);
    return 1.f - 2.f * __builtin_amdgcn_rcpf(e2 + 1.f);
}

__device__ __forceinline__ float fast_sigmoid(float x) {
    return __builtin_amdgcn_rcpf(1.f + __expf(-x));
}

// Kernel 1 (== R7, session best 61.4us): swapped-MFMA, NS=16, depth-2,
// block-contiguous btile mapping. Cold enc read runs at the machine's
// post-fill read ceiling (~4.9 TB/s); all request-shape/TLP/ILP variants
// measured 61.4-62.7us -> memory-floor bound.
__global__ __launch_bounds__(256, 2) void attn_kernel(
        const float* __restrict__ enc, const float* __restrict__ s_in,
        const float* __restrict__ W_attn, const float* __restrict__ b_attn,
        const float* __restrict__ v_attn,
        float* __restrict__ ctx_part, float* __restrict__ l_part,
        int NS, int chunk) {
    const int tid  = threadIdx.x;
    const int lane = tid & 63;
    const int w    = tid >> 6;                 // wave in block
    const int cid  = blockIdx.x % NS;          // S-chunk (shared by all 4 waves)
    const int btile = (blockIdx.x / NS) * 4 + w;  // 4 adjacent btiles per block
    const int b0 = btile * 16;
    const int lo = lane & 15;   // batch (B-frag col / D col)
    const int g  = lane >> 4;   // k-group; D rows d = 4g+j (+16t)

    short8 bW2[2][2];           // A-frag: W_attn[16t+lo][32+32cc+8g+e]
    f32x4 spre[2];
    float v0[4], v1[4];
    {
        const float* sp = s_in + (size_t)(b0 + lo) * 32 + 8 * g;
        float4 sa = *(const float4*)sp;
        float4 sb = *(const float4*)(sp + 4);
        short8 aS;                      // B-frag: s[b0+lo][8g+e]
        aS[0]=f2bf(sa.x); aS[1]=f2bf(sa.y); aS[2]=f2bf(sa.z); aS[3]=f2bf(sa.w);
        aS[4]=f2bf(sb.x); aS[5]=f2bf(sb.y); aS[6]=f2bf(sb.z); aS[7]=f2bf(sb.w);
#pragma unroll
        for (int t = 0; t < 2; ++t) {
            const float* wp = W_attn + (size_t)(16*t + lo) * 96 + 8 * g;
            float4 wa = *(const float4*)wp;
            float4 wb = *(const float4*)(wp + 4);
            short8 bW1;                 // A-frag: W_attn[16t+lo][8g+e]
            bW1[0]=f2bf(wa.x); bW1[1]=f2bf(wa.y); bW1[2]=f2bf(wa.z); bW1[3]=f2bf(wa.w);
            bW1[4]=f2bf(wb.x); bW1[5]=f2bf(wb.y); bW1[6]=f2bf(wb.z); bW1[7]=f2bf(wb.w);
            f32x4 ci;                   // seed at row d = 16t + 4g + j
#pragma unroll
            for (int j = 0; j < 4; ++j) ci[j] = b_attn[16*t + 4*g + j];
            spre[t] = __builtin_amdgcn_mfma_f32_16x16x32_bf16(bW1, aS, ci, 0, 0, 0);
#pragma unroll
            for (int cc = 0; cc < 2; ++cc) {
                const float* qp = W_attn + (size_t)(16*t + lo) * 96 + 32 + 32*cc + 8*g;
                float4 qa = *(const float4*)qp;
                float4 qb = *(const float4*)(qp + 4);
                short8 bb;
                bb[0]=f2bf(qa.x); bb[1]=f2bf(qa.y); bb[2]=f2bf(qa.z); bb[3]=f2bf(qa.w);
                bb[4]=f2bf(qb.x); bb[5]=f2bf(qb.y); bb[6]=f2bf(qb.z); bb[7]=f2bf(qb.w);
                bW2[t][cc] = bb;
            }
        }
#pragma unroll
        for (int j = 0; j < 4; ++j) { v0[j] = v_attn[4*g + j]; v1[j] = v_attn[16 + 4*g + j]; }
    }

    float ctx[16];
#pragma unroll
    for (int i = 0; i < 16; ++i) ctx[i] = 0.f;
    float l_acc = 0.f;

    const size_t rowstride = (size_t)2048 * 64;
    const float* pc = enc + (size_t)(cid * chunk) * rowstride + (size_t)(b0 + lo) * 64 + 8 * g;

    float4 c0a,c0b,c1a,c1b, n0a,n0b,n1a,n1b;
#define LOAD_ENC(P, A,Bq,C,D) { const float4* q = (const float4*)(P); A = q[0]; Bq = q[1]; C = q[8]; D = q[9]; }

#define BODY(A,Bq,C,D) { \
    short8 a0, a1; \
    a0[0]=f2bf(A.x); a0[1]=f2bf(A.y); a0[2]=f2bf(A.z); a0[3]=f2bf(A.w); \
    a0[4]=f2bf(Bq.x); a0[5]=f2bf(Bq.y); a0[6]=f2bf(Bq.z); a0[7]=f2bf(Bq.w); \
    a1[0]=f2bf(C.x); a1[1]=f2bf(C.y); a1[2]=f2bf(C.z); a1[3]=f2bf(C.w); \
    a1[4]=f2bf(D.x); a1[5]=f2bf(D.y); a1[6]=f2bf(D.z); a1[7]=f2bf(D.w); \
    f32x4 acc0 = __builtin_amdgcn_mfma_f32_16x16x32_bf16(bW2[0][0], a0, spre[0], 0,0,0); \
    acc0 = __builtin_amdgcn_mfma_f32_16x16x32_bf16(bW2[0][1], a1, acc0, 0,0,0); \
    f32x4 acc1 = __builtin_amdgcn_mfma_f32_16x16x32_bf16(bW2[1][0], a0, spre[1], 0,0,0); \
    acc1 = __builtin_amdgcn_mfma_f32_16x16x32_bf16(bW2[1][1], a1, acc1, 0,0,0); \
    float part = fast_tanh(acc0[0])*v0[0] + fast_tanh(acc0[1])*v0[1] \
               + fast_tanh(acc0[2])*v0[2] + fast_tanh(acc0[3])*v0[3] \
               + fast_tanh(acc1[0])*v1[0] + fast_tanh(acc1[1])*v1[1] \
               + fast_tanh(acc1[2])*v1[2] + fast_tanh(acc1[3])*v1[3]; \
    part += __shfl_xor(part, 16); \
    part += __shfl_xor(part, 32); \
    float w_ = __expf(part); \
    l_acc += w_; \
    ctx[0] += w_*A.x;  ctx[1] += w_*A.y;  ctx[2] += w_*A.z;  ctx[3] += w_*A.w; \
    ctx[4] += w_*Bq.x; ctx[5] += w_*Bq.y; ctx[6] += w_*Bq.z; ctx[7] += w_*Bq.w; \
    ctx[8] += w_*C.x;  ctx[9] += w_*C.y;  ctx[10] += w_*C.z; ctx[11] += w_*C.w; \
    ctx[12] += w_*D.x; ctx[13] += w_*D.y; ctx[14] += w_*D.z; ctx[15] += w_*D.w; \
}

    LOAD_ENC(pc, c0a, c0b, c1a, c1b);
    for (int i = 0; i < chunk; i += 2) {
        LOAD_ENC(pc + rowstride, n0a, n0b, n1a, n1b);
        BODY(c0a, c0b, c1a, c1b);
        if (i + 2 < chunk) { LOAD_ENC(pc + 2*rowstride, c0a, c0b, c1a, c1b); }
        BODY(n0a, n0b, n1a, n1b);
        pc += 2 * rowstride;
    }
#undef BODY
#undef LOAD_ENC

    float* cp = ctx_part + (size_t)(cid * 2048 + b0 + lo) * 64 + 8 * g;
    *(float4*)(cp)      = make_float4(ctx[0],  ctx[1],  ctx[2],  ctx[3]);
    *(float4*)(cp + 4)  = make_float4(ctx[4],  ctx[5],  ctx[6],  ctx[7]);
    *(float4*)(cp + 32) = make_float4(ctx[8],  ctx[9],  ctx[10], ctx[11]);
    *(float4*)(cp + 36) = make_float4(ctx[12], ctx[13], ctx[14], ctx[15]);
    if (lane < 16) l_part[cid * 2048 + b0 + lane] = l_acc;
}

// Kernel 2: reduce partials -> ctx, then emb + GRU + fc. 8 batches/block.
// R10: NS-reduce loop unrolled x4 with independent accumulators (12
// concurrent loads/step instead of 3) — this loop is what made NS=32
// cost +10.6us; at NS=16 it's still a few latency-bound us to claw back.
__global__ __launch_bounds__(256) void finish_kernel(
        const float* __restrict__ dec_in, const float* __restrict__ s_in,
        const float* __restrict__ W_emb, const float* __restrict__ b_emb,
        const float* __restrict__ W_ih, const float* __restrict__ W_hh,
        const float* __restrict__ b_ih, const float* __restrict__ b_hh,
        const float* __restrict__ W_fc, const float* __restrict__ b_fc,
        const float* __restrict__ ctx_part, const float* __restrict__ l_part,
        float* __restrict__ out, int NS) {
    __shared__ __align__(16) float x_lds[8][80];   // [emb(16); ctx(64)]
    __shared__ __align__(16) float s_lds[8][32];
    const int tid = threadIdx.x;
    const int bl = tid >> 5;
    const int h  = tid & 31;
    const int b  = blockIdx.x * 8 + bl;

    float c0a = 0.f, c0b = 0.f, c0c = 0.f, c0d = 0.f;
    float c1a = 0.f, c1b = 0.f, c1c = 0.f, c1d = 0.f;
    float lsa = 0.f, lsb = 0.f, lsc = 0.f, lsd = 0.f;
    for (int c = 0; c < NS; c += 4) {
        const float* p0 = ctx_part + (size_t)((c+0) * 2048 + b) * 64;
        const float* p1 = ctx_part + (size_t)((c+1) * 2048 + b) * 64;
        const float* p2 = ctx_part + (size_t)((c+2) * 2048 + b) * 64;
        const float* p3 = ctx_part + (size_t)((c+3) * 2048 + b) * 64;
        c0a += p0[h];      c0b += p1[h];      c0c += p2[h];      c0d += p3[h];
        c1a += p0[h + 32]; c1b += p1[h + 32]; c1c += p2[h + 32]; c1d += p3[h + 32];
        lsa += l_part[(c+0) * 2048 + b]; lsb += l_part[(c+1) * 2048 + b];
        lsc += l_part[(c+2) * 2048 + b]; lsd += l_part[(c+3) * 2048 + b];
    }
    float c0 = (c0a + c0b) + (c0c + c0d);
    float c1 = (c1a + c1b) + (c1c + c1d);
    float ls = (lsa + lsb) + (lsc + lsd);
    float inv = 1.f / ls;
    x_lds[bl][16 + h] = c0 * inv;
    x_lds[bl][48 + h] = c1 * inv;
    if (h < 16) x_lds[bl][h] = fmaxf(0.f, dec_in[b] * W_emb[h] + b_emb[h]);
    s_lds[bl][h] = s_in[b * 32 + h];
    __syncthreads();

    float a_r  = b_ih[h]      + b_hh[h];
    float a_z  = b_ih[32 + h] + b_hh[32 + h];
    float gi_n = b_ih[64 + h];
    float gh_n = b_hh[64 + h];
    const float4* xv4 = (const float4*)&x_lds[bl][0];
    const float4* wr4 = (const float4*)(W_ih + 80 * h);
    const float4* wz4 = (const float4*)(W_ih + 80 * (32 + h));
    const float4* wn4 = (const float4*)(W_ih + 80 * (64 + h));
#pragma unroll
    for (int j = 0; j < 20; ++j) {
        float4 x = xv4[j], wr = wr4[j], wz = wz4[j], wn = wn4[j];
        a_r  += x.x*wr.x + x.y*wr.y + x.z*wr.z + x.w*wr.w;
        a_z  += x.x*wz.x + x.y*wz.y + x.z*wz.z + x.w*wz.w;
        gi_n += x.x*wn.x + x.y*wn.y + x.z*wn.z + x.w*wn.w;
    }
    const float4* sv4 = (const float4*)&s_lds[bl][0];
    const float4* hr4 = (const float4*)(W_hh + 32 * h);
    const float4* hz4 = (const float4*)(W_hh + 32 * (32 + h));
    const float4* hn4 = (const float4*)(W_hh + 32 * (64 + h));
#pragma unroll
    for (int j = 0; j < 8; ++j) {
        float4 x = sv4[j], wr = hr4[j], wz = hz4[j], wn = hn4[j];
        a_r  += x.x*wr.x + x.y*wr.y + x.z*wr.z + x.w*wr.w;
        a_z  += x.x*wz.x + x.y*wz.y + x.z*wz.z + x.w*wz.w;
        gh_n += x.x*wn.x + x.y*wn.y + x.z*wn.z + x.w*wn.w;
    }
    float r = fast_sigmoid(a_r);
    float z = fast_sigmoid(a_z);
    float n = fast_tanh(gi_n + r * gh_n);
    float sv = s_lds[bl][h];
    float hn = (1.f - z) * n + z * sv;
    out[2048 + b * 32 + h] = hn;

    float p = hn * W_fc[h] + x_lds[bl][16 + h] * W_fc[32 + h] + x_lds[bl][48 + h] * W_fc[64 + h];
    if (h < 16) p += x_lds[bl][h] * W_fc[96 + h];
    p += __shfl_xor(p, 1); p += __shfl_xor(p, 2); p += __shfl_xor(p, 4);
    p += __shfl_xor(p, 8); p += __shfl_xor(p, 16);
    if (h == 0) out[b] = p + b_fc[0];
}

extern "C" void kernel_launch(void* const* d_in, const int* in_sizes, int n_in,
                              void* d_out, int out_size, void* d_ws, size_t ws_size,
                              hipStream_t stream) {
    const float* dec_in = (const float*)d_in[0];
    const float* s_in   = (const float*)d_in[1];
    const float* enc    = (const float*)d_in[2];
    const float* W_attn = (const float*)d_in[3];
    const float* b_attn = (const float*)d_in[4];
    const float* v_attn = (const float*)d_in[5];
    const float* W_emb  = (const float*)d_in[6];
    const float* b_emb  = (const float*)d_in[7];
    const float* W_ih   = (const float*)d_in[8];
    const float* W_hh   = (const float*)d_in[9];
    const float* b_ih   = (const float*)d_in[10];
    const float* b_hh   = (const float*)d_in[11];
    const float* W_fc   = (const float*)d_in[12];
    const float* b_fc   = (const float*)d_in[13];
    float* out = (float*)d_out;

    int NS = 16;
    while (NS > 4 && (size_t)NS * (2048u * 64u + 2048u) * sizeof(float) > ws_size) NS >>= 1;
    int chunk = 512 / NS;
    float* ctx_part = (float*)d_ws;                       // [NS][2048][64]
    float* l_part   = ctx_part + (size_t)NS * 2048 * 64;  // [NS][2048]

    attn_kernel<<<dim3(32 * NS), dim3(256), 0, stream>>>(
        enc, s_in, W_attn, b_attn, v_attn, ctx_part, l_part, NS, chunk);
    finish_kernel<<<dim3(256), dim3(256), 0, stream>>>(
        dec_in, s_in, W_emb, b_emb, W_ih, W_hh, b_ih, b_hh, W_fc, b_fc,
        ctx_part, l_part, out, NS);
}